// Round 11
// baseline (627.695 us; speedup 1.0000x reference)
//
#include <hip/hip_runtime.h>

#define B_  16
#define T_  512
#define M_  2048
#define C_  512
#define NEGV (-1e30f)
#define L2E 1.4426950408889634f
#define LN2 0.69314718055994531f

typedef unsigned short u16;
typedef unsigned int   u32;
using bf16x8 = __attribute__((ext_vector_type(8))) short;
using f32x4  = __attribute__((ext_vector_type(4))) float;

__device__ __forceinline__ u16 f2bf(float x) {
  u32 u = __float_as_uint(x);
  return (u16)((u + 0x7FFFu + ((u >> 16) & 1u)) >> 16);
}
__device__ __forceinline__ float bf2f(u16 u) {
  return __uint_as_float(((u32)u) << 16);
}
__device__ __forceinline__ float rdlane63(float x) {
  return __int_as_float(__builtin_amdgcn_readlane(__float_as_int(x), 63));
}

// 64-lane inclusive add-scan via DPP (row_shr 1/2/4/8, bcast15, bcast31)
__device__ __forceinline__ float wscan_add(float x) {
  x += __int_as_float(__builtin_amdgcn_update_dpp(0, __float_as_int(x), 0x111, 0xF, 0xF, true));
  x += __int_as_float(__builtin_amdgcn_update_dpp(0, __float_as_int(x), 0x112, 0xF, 0xF, true));
  x += __int_as_float(__builtin_amdgcn_update_dpp(0, __float_as_int(x), 0x114, 0xF, 0xF, true));
  x += __int_as_float(__builtin_amdgcn_update_dpp(0, __float_as_int(x), 0x118, 0xF, 0xF, true));
  x += __int_as_float(__builtin_amdgcn_update_dpp(0, __float_as_int(x), 0x142, 0xA, 0xF, true));
  x += __int_as_float(__builtin_amdgcn_update_dpp(0, __float_as_int(x), 0x143, 0xC, 0xF, true));
  return x;
}
// lane i <- lane i-1 (wave_shr:1), lane0 <- 0
__device__ __forceinline__ float dpp_shr1(float x) {
  return __int_as_float(__builtin_amdgcn_update_dpp(0, __float_as_int(x), 0x138, 0xF, 0xF, true));
}

// ---------------------------------------------------------------------------
// K1: energy GEMM (bf16 MFMA) + gumbel + /temperature -> tt = exp(le - D) bf16
// ---------------------------------------------------------------------------
__launch_bounds__(256)
__global__ void k1_energy(const float* __restrict__ text, const float* __restrict__ mel,
                          const float* __restrict__ noise, const float* __restrict__ ratio,
                          u16* __restrict__ ttbuf)
{
  __shared__ __align__(16) short As[128][40];
  __shared__ __align__(16) short Bs[128][40];
  const int b   = blockIdx.z;
  const int t0  = blockIdx.x * 128;
  const int m0  = blockIdx.y * 128;
  const int tid = threadIdx.x;
  const int lane = tid & 63, wid = tid >> 6;
  const int wr = wid >> 1, wc = wid & 1;
  const float* Ab = text + (size_t)b * T_ * C_;
  const float* Bb = mel  + (size_t)b * M_ * C_;
  f32x4 acc[4][4];
#pragma unroll
  for (int i = 0; i < 4; ++i)
#pragma unroll
    for (int j = 0; j < 4; ++j) acc[i][j] = (f32x4){0.f, 0.f, 0.f, 0.f};

  const int kq = (tid & 7) * 4;
  const int rb = tid >> 3;
  for (int kk = 0; kk < C_; kk += 32) {
    __syncthreads();
#pragma unroll
    for (int it = 0; it < 4; ++it) {
      int r = rb + it * 32;
      float4 va = *(const float4*)(Ab + (size_t)(t0 + r) * C_ + kk + kq);
      As[r][kq + 0] = (short)f2bf(va.x); As[r][kq + 1] = (short)f2bf(va.y);
      As[r][kq + 2] = (short)f2bf(va.z); As[r][kq + 3] = (short)f2bf(va.w);
      float4 vb = *(const float4*)(Bb + (size_t)(m0 + r) * C_ + kk + kq);
      Bs[r][kq + 0] = (short)f2bf(vb.x); Bs[r][kq + 1] = (short)f2bf(vb.y);
      Bs[r][kq + 2] = (short)f2bf(vb.z); Bs[r][kq + 3] = (short)f2bf(vb.w);
    }
    __syncthreads();
    const int k0 = (lane >> 4) * 8;
    bf16x8 af[4], bfr[4];
#pragma unroll
    for (int i = 0; i < 4; ++i) {
      af[i]  = *(const bf16x8*)&As[wr * 64 + i * 16 + (lane & 15)][k0];
      bfr[i] = *(const bf16x8*)&Bs[wc * 64 + i * 16 + (lane & 15)][k0];
    }
#pragma unroll
    for (int i = 0; i < 4; ++i)
#pragma unroll
      for (int j = 0; j < 4; ++j)
        acc[i][j] = __builtin_amdgcn_mfma_f32_16x16x32_bf16(af[i], bfr[j], acc[i][j], 0, 0, 0);
  }
  const float invT = 1.0f / (0.1f + 0.9f * ratio[0]);
  const float D2 = 14.5f * invT * L2E;
#pragma unroll
  for (int i = 0; i < 4; ++i) {
#pragma unroll
    for (int j = 0; j < 4; ++j) {
#pragma unroll
      for (int rr = 0; rr < 4; ++rr) {
        int t = t0 + wr * 64 + i * 16 + (lane >> 4) * 4 + rr;
        int m = m0 + wc * 64 + j * 16 + (lane & 15);
        size_t idx = ((size_t)b * T_ + t) * M_ + m;
        float en = acc[i][j][rr] * (1.0f / 512.0f);
        float u  = noise[idx];
        float nl = -LN2 * __builtin_amdgcn_logf(u);    // -ln u  (>0)
        float g  = -LN2 * __builtin_amdgcn_logf(nl);   // -ln(-ln u)
        float le = (en + g) * invT;
        float tv = __builtin_amdgcn_exp2f(__builtin_fmaf(le, L2E, -D2));
        ttbuf[idx] = f2bf(tv);
      }
    }
  }
}

// ---------------------------------------------------------------------------
// K2u: per row t: suffix-sums of tt[t], tt[t+1] -> R_t, R_{t+1} in regs;
//      W[t]=tt_t*R_t; UB[t]=tt_t*R_{t+1}; UA[t+1][k]=tt_t[k-1]*R_{t+1}[k];
//      row T-1: Q init = S_{T-1} (x e at col M-1) -> Bbuf; t=0: r00[b]=R_0[0].
// ---------------------------------------------------------------------------
__launch_bounds__(256)
__global__ void k2u(const u16* __restrict__ tt, u16* __restrict__ W,
                    u16* __restrict__ UA, u16* __restrict__ UB,
                    u16* __restrict__ Qb, float* __restrict__ r00)
{
  __shared__ float part0[4], part1[4];
  const size_t row = blockIdx.x;               // b*T + t
  const int t = (int)(row & (T_ - 1));
  const int b = (int)(row >> 9);
  const size_t rowN = (t < T_ - 1) ? row + 1 : row;
  const int tid = threadIdx.x, lane = tid & 63, wid = tid >> 6;
  const int c0 = tid * 8;
  const u16* ttr = tt + row * M_ + c0;
  const u16* ttn = tt + rowN * M_ + c0;
  float x[8], y[8];
  { uint4 wa = *(const uint4*)ttr;
    x[0]=__uint_as_float(wa.x<<16); x[1]=__uint_as_float(wa.x&0xFFFF0000u);
    x[2]=__uint_as_float(wa.y<<16); x[3]=__uint_as_float(wa.y&0xFFFF0000u);
    x[4]=__uint_as_float(wa.z<<16); x[5]=__uint_as_float(wa.z&0xFFFF0000u);
    x[6]=__uint_as_float(wa.w<<16); x[7]=__uint_as_float(wa.w&0xFFFF0000u); }
  { uint4 wb = *(const uint4*)ttn;
    y[0]=__uint_as_float(wb.x<<16); y[1]=__uint_as_float(wb.x&0xFFFF0000u);
    y[2]=__uint_as_float(wb.y<<16); y[3]=__uint_as_float(wb.y&0xFFFF0000u);
    y[4]=__uint_as_float(wb.z<<16); y[5]=__uint_as_float(wb.z&0xFFFF0000u);
    y[6]=__uint_as_float(wb.w<<16); y[7]=__uint_as_float(wb.w&0xFFFF0000u); }
  float xm1 = (c0 == 0) ? 0.f : bf2f(ttr[-1]);

  float sx[8], sy[8];
  sx[7] = x[7]; sy[7] = y[7];
#pragma unroll
  for (int i = 6; i >= 0; --i) { sx[i] = x[i] + sx[i+1]; sy[i] = y[i] + sy[i+1]; }
  float vx = sx[0], vy = sy[0];
#pragma unroll
  for (int d = 1; d < 64; d <<= 1) {
    float tx = __shfl_down(vx, d), ty = __shfl_down(vy, d);
    if (lane < 64 - d) { vx += tx; vy += ty; }
  }
  float ex = __shfl_down(vx, 1), ey = __shfl_down(vy, 1);
  if (lane == 63) { ex = 0.f; ey = 0.f; }
  if (lane == 0) { part0[wid] = vx; part1[wid] = vy; }
  __syncthreads();
  float wex = 0.f, wey = 0.f;
  for (int w2 = wid + 1; w2 < 4; ++w2) { wex += part0[w2]; wey += part1[w2]; }
  float offx = ex + wex, offy = ey + wey;

  float rx[8], ry[8];
#pragma unroll
  for (int i = 0; i < 8; ++i) {
    rx[i] = __builtin_amdgcn_rcpf(sx[i] + offx);
    ry[i] = __builtin_amdgcn_rcpf(sy[i] + offy);
  }
  // W[t]
  { u32 o[4];
#pragma unroll
    for (int i = 0; i < 4; ++i)
      o[i] = __builtin_amdgcn_perm(__float_as_uint(x[2*i+1]*rx[2*i+1]),
                                   __float_as_uint(x[2*i]*rx[2*i]), 0x07060302u);
    *(uint4*)(W + row * M_ + c0) = make_uint4(o[0],o[1],o[2],o[3]); }

  if (t == 0 && tid == 0) r00[b] = rx[0];

  if (t == T_ - 1) {
    float q[8];
#pragma unroll
    for (int i = 0; i < 8; ++i) q[i] = sx[i] + offx;
    if (tid == 255) q[7] *= 2.718281828f;      // faithful beta_T[M-1]=1 -> e
    u32 o[4];
#pragma unroll
    for (int i = 0; i < 4; ++i)
      o[i] = __builtin_amdgcn_perm(__float_as_uint(q[2*i+1]), __float_as_uint(q[2*i]), 0x07060302u);
    *(uint4*)(Qb + ((size_t)b * T_ + T_ - 1) * M_ + c0) = make_uint4(o[0],o[1],o[2],o[3]);
  } else {
    u32 o[4];
#pragma unroll
    for (int i = 0; i < 4; ++i)
      o[i] = __builtin_amdgcn_perm(__float_as_uint(x[2*i+1]*ry[2*i+1]),
                                   __float_as_uint(x[2*i]*ry[2*i]), 0x07060302u);
    *(uint4*)(UB + row * M_ + c0) = make_uint4(o[0],o[1],o[2],o[3]);
    float ua[8];
    ua[0] = xm1 * ry[0];
#pragma unroll
    for (int i = 1; i < 8; ++i) ua[i] = x[i-1] * ry[i];
#pragma unroll
    for (int i = 0; i < 4; ++i)
      o[i] = __builtin_amdgcn_perm(__float_as_uint(ua[2*i+1]), __float_as_uint(ua[2*i]), 0x07060302u);
    *(uint4*)(UA + (row + 1) * M_ + c0) = make_uint4(o[0],o[1],o[2],o[3]);
  }
}

// ---------------------------------------------------------------------------
// K3a/K3b: suffix sums of text over t; K3t: textT transpose (unchanged)
// ---------------------------------------------------------------------------
__launch_bounds__(512)
__global__ void k3a_partial(const float* __restrict__ text, float* __restrict__ partial)
{
  const int b = blockIdx.x >> 3, ch = blockIdx.x & 7, c = threadIdx.x;
  const float* tb = text + (size_t)b * T_ * C_ + (size_t)ch * 64 * C_ + c;
  float s = 0.f;
#pragma unroll 8
  for (int tt = 0; tt < 64; ++tt) s += tb[(size_t)tt * C_];
  partial[((size_t)b * 8 + ch) * C_ + c] = s;
}

__launch_bounds__(512)
__global__ void k3b_suffix(const float* __restrict__ text, const float* __restrict__ partial,
                           float* __restrict__ suffix)
{
  const int b = blockIdx.x >> 3, ch = blockIdx.x & 7, c = threadIdx.x;
  float off = 0.f;
  for (int ch2 = ch + 1; ch2 < 8; ++ch2) off += partial[((size_t)b * 8 + ch2) * C_ + c];
  const float* tb = text + (size_t)b * T_ * C_ + (size_t)ch * 64 * C_ + c;
  float* sb = suffix + (size_t)b * (T_ + 1) * C_ + (size_t)ch * 64 * C_ + c;
  if (ch == 7) sb[(size_t)64 * C_] = 0.f;   // row T_
  float s = off;
  for (int tt = 63; tt >= 0; --tt) {
    s += tb[(size_t)tt * C_];
    sb[(size_t)tt * C_] = s;
  }
}

__launch_bounds__(256)
__global__ void k3t_textT(const float* __restrict__ text, u16* __restrict__ textT)
{
  __shared__ u16 tile[64][66];
  const int b  = blockIdx.z;
  const int t0 = blockIdx.x * 64;
  const int c0 = blockIdx.y * 64;
  const int tid = threadIdx.x;
  const int j = tid & 63, i4 = tid >> 6;
#pragma unroll
  for (int it = 0; it < 16; ++it) {
    int i = it * 4 + i4;
    tile[i][j] = f2bf(text[((size_t)b * T_ + t0 + i) * C_ + c0 + j]);
  }
  __syncthreads();
#pragma unroll
  for (int it = 0; it < 16; ++it) {
    int cc = it * 4 + i4;
    textT[((size_t)b * C_ + c0 + cc) * T_ + t0 + j] = tile[j][cc];
  }
}

// ---------------------------------------------------------------------------
// K4: alpha (blocks 0..15) / beta (blocks 16..31). 128 threads/block:
//     wave 0 = round-8 DP (plain HIP, proven); wave 1 = prefetch "warmer"
//     streaming the same U rows <=40 ahead (paced via volatile-LDS progress),
//     converting the DP wave's sunk-load misses into L1/L2 hits.
// ---------------------------------------------------------------------------
__launch_bounds__(128, 1)
__global__ void k4_dp(const u16* __restrict__ UA, const u16* __restrict__ UB,
                      const float* __restrict__ r00,
                      u16* __restrict__ Abuf, u16* __restrict__ Bbuf,
                      float* __restrict__ CAa, float* __restrict__ CBa)
{
  __shared__ int prog;
  const int blk = blockIdx.x;
  const int b   = blk & 15;
  const int tid = threadIdx.x;
  const int lane = tid & 63;
  const int wv   = tid >> 6;
  uint4 raw[2][4];
  float cum[32], Pv[32];
  float Cv;

  if (tid == 0) prog = 0;
  __syncthreads();

  if (blk < 16) {
    // ======================= alpha =======================
    const int c0 = lane * 32;
    const u16* Up = UA + (size_t)b * T_ * M_;

    if (wv == 1) {
      // ---- warmer wave: rows 1..511, <=40 ahead of DP step ----
      u32 acc = 0;
      for (int w = 1; w < T_; ) {
        int p = *(volatile int*)&prog;
        if (w <= p + 40) {
#pragma unroll
          for (int k = 0; k < 4; ++k) {
            int rr = (w + k < T_) ? w + k : T_ - 1;
            const uint4* q = (const uint4*)(Up + (size_t)rr * M_ + c0);
            uint4 a0 = q[0], a1 = q[1], a2 = q[2], a3 = q[3];
            acc ^= a0.x ^ a1.y ^ a2.z ^ a3.w;
          }
          w += 4;
        } else {
          __builtin_amdgcn_s_sleep(2);
        }
      }
      asm volatile("" :: "v"(acc));
      return;
    }

    u16* AO = Abuf + (size_t)b * T_ * M_;
    float* CO = CAa + (size_t)b * T_;

#define TLDA(BUF, R) { const uint4* p_ = (const uint4*)(Up + (size_t)(R) * M_ + c0); \
    raw[BUF][0]=p_[0]; raw[BUF][1]=p_[1]; raw[BUF][2]=p_[2]; raw[BUF][3]=p_[3]; }

#define AF2(E, W_) { \
    cum[E]     = __uint_as_float((W_) << 16)         * Pv[(E)-1]; \
    cum[(E)+1] = __uint_as_float((W_) & 0xFFFF0000u) * Pv[E]; }

#define ASTEP(BUF, RIDX) { \
    const int r_ = (RIDX); \
    { float pm1 = dpp_shr1(Pv[31]); \
      u32 w0 = raw[BUF][0].x; \
      cum[0] = __uint_as_float(w0 << 16) * pm1; \
      cum[1] = __uint_as_float(w0 & 0xFFFF0000u) * Pv[0]; } \
    AF2(2,  raw[BUF][0].y) AF2(4,  raw[BUF][0].z) AF2(6,  raw[BUF][0].w) \
    AF2(8,  raw[BUF][1].x) AF2(10, raw[BUF][1].y) AF2(12, raw[BUF][1].z) AF2(14, raw[BUF][1].w) \
    AF2(16, raw[BUF][2].x) AF2(18, raw[BUF][2].y) AF2(20, raw[BUF][2].z) AF2(22, raw[BUF][2].w) \
    AF2(24, raw[BUF][3].x) AF2(26, raw[BUF][3].y) AF2(28, raw[BUF][3].z) AF2(30, raw[BUF][3].w) \
    _Pragma("unroll") for (int c = 0; c < 4; ++c) \
      _Pragma("unroll") for (int k = 1; k < 8; ++k) cum[8*c+k] += cum[8*c+k-1]; \
    { float lt = (cum[7] + cum[15]) + (cum[23] + cum[31]); \
      float v_ = wscan_add(lt); \
      float exw = v_ - lt; \
      float Zt = rdlane63(v_); \
      float f0 = exw, f1 = f0 + cum[7], f2 = f1 + cum[15], f3 = f2 + cum[23]; \
      float Zc = fmaxf(Zt, 1e-35f); \
      float zr = __builtin_amdgcn_rcpf(Zc); \
      Cv += LN2 * __builtin_amdgcn_logf(Zc); \
      if (lane == 0) { CO[r_] = Cv; *(volatile int*)&prog = r_; } \
      float fz0 = f0*zr, fz1 = f1*zr, fz2 = f2*zr, fz3 = f3*zr; \
      _Pragma("unroll") for (int k = 0; k < 8; ++k) { \
        Pv[k]    = __builtin_fmaf(cum[k],    zr, fz0); \
        Pv[8+k]  = __builtin_fmaf(cum[8+k],  zr, fz1); \
        Pv[16+k] = __builtin_fmaf(cum[16+k], zr, fz2); \
        Pv[24+k] = __builtin_fmaf(cum[24+k], zr, fz3); } } \
    { u32 w_[16]; \
      _Pragma("unroll") for (int d = 0; d < 16; ++d) \
        w_[d] = __builtin_amdgcn_perm(__float_as_uint(Pv[2*d+1]), __float_as_uint(Pv[2*d]), 0x07060302u); \
      uint4* op = (uint4*)(AO + (size_t)r_ * M_ + c0); \
      op[0] = make_uint4(w_[0],w_[1],w_[2],w_[3]); \
      op[1] = make_uint4(w_[4],w_[5],w_[6],w_[7]); \
      op[2] = make_uint4(w_[8],w_[9],w_[10],w_[11]); \
      op[3] = make_uint4(w_[12],w_[13],w_[14],w_[15]); } \
    TLDA(BUF, (r_ + 2 < T_) ? r_ + 2 : T_ - 1) \
    __builtin_amdgcn_sched_barrier(0); \
  }

    // init: P row 0 = 1.0 everywhere; CA_0 = ln(R_0[0])
    { uint4 one4 = make_uint4(0x3F803F80u, 0x3F803F80u, 0x3F803F80u, 0x3F803F80u);
      uint4* op = (uint4*)(AO + c0);
      op[0] = one4; op[1] = one4; op[2] = one4; op[3] = one4; }
    Cv = LN2 * __builtin_amdgcn_logf(r00[b]);
    if (lane == 0) CO[0] = Cv;
#pragma unroll
    for (int e = 0; e < 32; ++e) Pv[e] = 1.0f;

    TLDA(0, 1) TLDA(1, 2)
    for (int r = 1; r + 1 < T_; r += 2) {
      ASTEP(0, r)
      ASTEP(1, r + 1)
    }
    ASTEP(0, T_ - 1)
  } else {
    // ======================= beta (memory order, mirrored scans) ==========
    const int jb = M_ - 32 - lane * 32;   // lane covers cols jb..jb+31 ascending
    const u16* Up = UB + (size_t)b * T_ * M_;

    if (wv == 1) {
      // ---- warmer wave: rows 510 down to 0, <=40 steps ahead of DP ----
      u32 acc = 0;
      for (int w = 0; w <= 510; ) {
        int p = *(volatile int*)&prog;
        if (w <= p + 40) {
#pragma unroll
          for (int k = 0; k < 4; ++k) {
            int rr = 510 - (w + k);
            if (rr < 0) rr = 0;
            const uint4* q = (const uint4*)(Up + (size_t)rr * M_ + jb);
            uint4 a0 = q[0], a1 = q[1], a2 = q[2], a3 = q[3];
            acc ^= a0.x ^ a1.y ^ a2.z ^ a3.w;
          }
          w += 4;
        } else {
          __builtin_amdgcn_s_sleep(2);
        }
      }
      asm volatile("" :: "v"(acc));
      return;
    }

    u16* BO = Bbuf + (size_t)b * T_ * M_;
    float* CO = CBa + (size_t)b * T_;

#define TLDB(BUF, R) { const uint4* p_ = (const uint4*)(Up + (size_t)(R) * M_ + jb); \
    raw[BUF][0]=p_[0]; raw[BUF][1]=p_[1]; raw[BUF][2]=p_[2]; raw[BUF][3]=p_[3]; }

#define BF2(E, W_) { \
    cum[E]     = __uint_as_float((W_) << 16)         * Pv[E]; \
    cum[(E)+1] = __uint_as_float((W_) & 0xFFFF0000u) * Pv[(E)+1]; }

#define BSTEP(BUF, TIDX) { \
    const int t_ = (TIDX); \
    BF2(0,  raw[BUF][0].x) BF2(2,  raw[BUF][0].y) BF2(4,  raw[BUF][0].z) BF2(6,  raw[BUF][0].w) \
    BF2(8,  raw[BUF][1].x) BF2(10, raw[BUF][1].y) BF2(12, raw[BUF][1].z) BF2(14, raw[BUF][1].w) \
    BF2(16, raw[BUF][2].x) BF2(18, raw[BUF][2].y) BF2(20, raw[BUF][2].z) BF2(22, raw[BUF][2].w) \
    BF2(24, raw[BUF][3].x) BF2(26, raw[BUF][3].y) BF2(28, raw[BUF][3].z) BF2(30, raw[BUF][3].w) \
    _Pragma("unroll") for (int c = 0; c < 4; ++c) \
      _Pragma("unroll") for (int k = 6; k >= 0; --k) cum[8*c+k] += cum[8*c+k+1]; \
    { float lt = (cum[0] + cum[8]) + (cum[16] + cum[24]); \
      float v_ = wscan_add(lt); \
      float exw = v_ - lt; \
      float Zb = rdlane63(v_); \
      float f0 = exw, f1 = f0 + cum[24], f2 = f1 + cum[16], f3 = f2 + cum[8]; \
      float Zc = fmaxf(Zb, 1e-35f); \
      float zr = __builtin_amdgcn_rcpf(Zc); \
      Cv += LN2 * __builtin_amdgcn_logf(Zc); \
      if (lane == 0) { CO[t_] = Cv; *(volatile int*)&prog = 510 - t_; } \
      float fz0 = f0*zr, fz1 = f1*zr, fz2 = f2*zr, fz3 = f3*zr; \
      _Pragma("unroll") for (int k = 0; k < 8; ++k) { \
        Pv[24+k] = __builtin_fmaf(cum[24+k], zr, fz0); \
        Pv[16+k] = __builtin_fmaf(cum[16+k], zr, fz1); \
        Pv[8+k]  = __builtin_fmaf(cum[8+k],  zr, fz2); \
        Pv[k]    = __builtin_fmaf(cum[k],    zr, fz3); } } \
    { u32 w_[16]; \
      _Pragma("unroll") for (int d = 0; d < 16; ++d) \
        w_[d] = __builtin_amdgcn_perm(__float_as_uint(Pv[2*d+1]), __float_as_uint(Pv[2*d]), 0x07060302u); \
      uint4* op = (uint4*)(BO + (size_t)t_ * M_ + jb); \
      op[0] = make_uint4(w_[0],w_[1],w_[2],w_[3]); \
      op[1] = make_uint4(w_[4],w_[5],w_[6],w_[7]); \
      op[2] = make_uint4(w_[8],w_[9],w_[10],w_[11]); \
      op[3] = make_uint4(w_[12],w_[13],w_[14],w_[15]); } \
    TLDB(BUF, (t_ - 2 >= 0) ? t_ - 2 : 0) \
    __builtin_amdgcn_sched_barrier(0); \
  }

    // init: Q row T-1 (written by k2u) -> state; CB_{T-1} = 0
    { const uint4* ip = (const uint4*)(BO + (size_t)(T_ - 1) * M_ + jb);
      uint4 q0 = ip[0], q1 = ip[1], q2 = ip[2], q3 = ip[3];
      Pv[0]=__uint_as_float(q0.x<<16);  Pv[1]=__uint_as_float(q0.x&0xFFFF0000u);
      Pv[2]=__uint_as_float(q0.y<<16);  Pv[3]=__uint_as_float(q0.y&0xFFFF0000u);
      Pv[4]=__uint_as_float(q0.z<<16);  Pv[5]=__uint_as_float(q0.z&0xFFFF0000u);
      Pv[6]=__uint_as_float(q0.w<<16);  Pv[7]=__uint_as_float(q0.w&0xFFFF0000u);
      Pv[8]=__uint_as_float(q1.x<<16);  Pv[9]=__uint_as_float(q1.x&0xFFFF0000u);
      Pv[10]=__uint_as_float(q1.y<<16); Pv[11]=__uint_as_float(q1.y&0xFFFF0000u);
      Pv[12]=__uint_as_float(q1.z<<16); Pv[13]=__uint_as_float(q1.z&0xFFFF0000u);
      Pv[14]=__uint_as_float(q1.w<<16); Pv[15]=__uint_as_float(q1.w&0xFFFF0000u);
      Pv[16]=__uint_as_float(q2.x<<16); Pv[17]=__uint_as_float(q2.x&0xFFFF0000u);
      Pv[18]=__uint_as_float(q2.y<<16); Pv[19]=__uint_as_float(q2.y&0xFFFF0000u);
      Pv[20]=__uint_as_float(q2.z<<16); Pv[21]=__uint_as_float(q2.z&0xFFFF0000u);
      Pv[22]=__uint_as_float(q2.w<<16); Pv[23]=__uint_as_float(q2.w&0xFFFF0000u);
      Pv[24]=__uint_as_float(q3.x<<16); Pv[25]=__uint_as_float(q3.x&0xFFFF0000u);
      Pv[26]=__uint_as_float(q3.y<<16); Pv[27]=__uint_as_float(q3.y&0xFFFF0000u);
      Pv[28]=__uint_as_float(q3.z<<16); Pv[29]=__uint_as_float(q3.z&0xFFFF0000u);
      Pv[30]=__uint_as_float(q3.w<<16); Pv[31]=__uint_as_float(q3.w&0xFFFF0000u); }
    Cv = 0.f;
    if (lane == 0) CO[T_ - 1] = 0.f;

    TLDB(0, T_ - 2) TLDB(1, T_ - 3)
    for (int t = T_ - 2; t >= 2; t -= 2) {
      BSTEP(0, t)
      BSTEP(1, t - 1)
    }
    BSTEP(0, 0)
  }
}

// ---------------------------------------------------------------------------
// K6: gamma = (t<=m) ? LN2*log2(P*Q*W) + CA[t]+CB[t] : NEGV  (clamped);
//     LSE over t; gamma_log -> d_out; gammaT bf16 (masked) via LDS stash.
// ---------------------------------------------------------------------------
__launch_bounds__(256)
__global__ void k6_combine(const u16* __restrict__ Pb, const u16* __restrict__ Qb,
                           const u16* __restrict__ Wb,
                           const float* __restrict__ CAa, const float* __restrict__ CBa,
                           float* __restrict__ gamma_log, u16* __restrict__ gammaT)
{
  __shared__ u16 gst[32][514];
  __shared__ float cd[T_];
  __shared__ float smx[8][32], ssm[8][32];
  const int b  = blockIdx.x >> 6;
  const int m0 = (blockIdx.x & 63) * 32;
  const int tid = threadIdx.x;
  const int mi = tid & 31, ti = tid >> 5;
  const int m = m0 + mi;
  const size_t base = (size_t)b * T_ * M_ + m;

  cd[tid]       = CAa[b * T_ + tid]       + CBa[b * T_ + tid];
  cd[tid + 256] = CAa[b * T_ + tid + 256] + CBa[b * T_ + tid + 256];
  __syncthreads();

  float mx = -3.0e38f, s = 0.f;
  for (int t = ti; t < T_; t += 8) {
    float p  = bf2f(Pb[base + (size_t)t * M_]);
    float q  = bf2f(Qb[base + (size_t)t * M_]);
    float wv = bf2f(Wb[base + (size_t)t * M_]);
    float g;
    if (t <= m) {
      g = __builtin_fmaf(__builtin_amdgcn_logf(p * q * wv), LN2, cd[t]);
      g = fmaxf(g, -1e8f);            // underflow clamp (error << thresholds)
    } else g = NEGV;
    gst[mi][t] = f2bf(g);
    if (g > mx) { s = s * __builtin_amdgcn_exp2f((mx - g) * L2E) + 1.f; mx = g; }
    else        { s += __builtin_amdgcn_exp2f((g - mx) * L2E); }
  }
  smx[ti][mi] = mx; ssm[ti][mi] = s;
  __syncthreads();
  float Mv = smx[0][mi], Sv = ssm[0][mi];
#pragma unroll
  for (int k = 1; k < 8; ++k) {
    float Mk = smx[k][mi], Sk = ssm[k][mi];
    if (Mk > Mv) { Sv = Sv * __builtin_amdgcn_exp2f((Mv - Mk) * L2E) + Sk; Mv = Mk; }
    else         { Sv += Sk * __builtin_amdgcn_exp2f((Mk - Mv) * L2E); }
  }
  const float lse = Mv + LN2 * __builtin_amdgcn_logf(Sv);

  // pass2a: gamma_log (masked entries exact NEGV, not bf16-rounded)
  for (int t = ti; t < T_; t += 8) {
    float g = (t <= m) ? bf2f(gst[mi][t]) : NEGV;
    gamma_log[base + (size_t)t * M_] = g - lse;
  }
  // pass2b: gammaT[b, m0+k, t] from LDS stash (coalesced u32 rows)
  for (int k = 0; k < 32; ++k) {
    u32 val = *(const u32*)&gst[k][2 * tid];
    int mr = m0 + k;
    u32 lo = (2 * tid     <= mr) ? (val & 0x0000FFFFu) : 0u;
    u32 hi = (2 * tid + 1 <= mr) ? (val & 0xFFFF0000u) : 0u;
    ((u32*)gammaT)[((((size_t)b * M_ + m0 + k) * T_) >> 1) + tid] = lo | hi;
  }
}

// ---------------------------------------------------------------------------
// K7: expanded[b,m,c] = sum_t gammaT[m,t]*textT[c,t]  + (-1e30)*suffix[m+1,c]
// ---------------------------------------------------------------------------
__launch_bounds__(256)
__global__ void k7_expanded(const u16* __restrict__ gammaT, const u16* __restrict__ textT,
                            const float* __restrict__ suffix, float* __restrict__ expanded)
{
  __shared__ __align__(16) short As[128][40];
  __shared__ __align__(16) short Bs[128][40];
  const int b   = blockIdx.z;
  const int m0  = blockIdx.x * 128;
  const int c0  = blockIdx.y * 128;
  const int tid = threadIdx.x;
  const int lane = tid & 63, wid = tid >> 6;
  const int wr = wid >> 1, wc = wid & 1;
  const u16* Ab = gammaT + (size_t)b * M_ * T_;
  const u16* Bb = textT  + (size_t)b * C_ * T_;
  f32x4 acc[4][4];
#pragma unroll
  for (int i = 0; i < 4; ++i)
#pragma unroll
    for (int j = 0; j < 4; ++j) acc[i][j] = (f32x4){0.f, 0.f, 0.f, 0.f};

  const int ko  = (tid & 3) * 8;
  const int rb2 = tid >> 2;
  for (int kk = 0; kk < T_; kk += 32) {
    __syncthreads();
#pragma unroll
    for (int it = 0; it < 2; ++it) {
      int r = rb2 + it * 64;
      *(uint4*)&As[r][ko] = *(const uint4*)(Ab + (size_t)(m0 + r) * T_ + kk + ko);
      *(uint4*)&Bs[r][ko] = *(const uint4*)(Bb + (size_t)(c0 + r) * T_ + kk + ko);
    }
    __syncthreads();
    const int k0 = (lane >> 4) * 8;
    bf16x8 af[4], bfr[4];
#pragma unroll
    for (int i = 0; i < 4; ++i) {
      af[i]  = *(const bf16x8*)&As[wr * 64 + i * 16 + (lane & 15)][k0];
      bfr[i] = *(const bf16x8*)&Bs[wc * 64 + i * 16 + (lane & 15)][k0];
    }
#pragma unroll
    for (int i = 0; i < 4; ++i)
#pragma unroll
      for (int j = 0; j < 4; ++j)
        acc[i][j] = __builtin_amdgcn_mfma_f32_16x16x32_bf16(af[i], bfr[j], acc[i][j], 0, 0, 0);
  }
#pragma unroll
  for (int i = 0; i < 4; ++i) {
#pragma unroll
    for (int j = 0; j < 4; ++j) {
#pragma unroll
      for (int rr = 0; rr < 4; ++rr) {
        int m = m0 + wr * 64 + i * 16 + (lane >> 4) * 4 + rr;
        int c = c0 + wc * 64 + j * 16 + (lane & 15);
        int sidx = (m + 1 < T_) ? (m + 1) : T_;
        float sfx = suffix[((size_t)b * (T_ + 1) + sidx) * C_ + c];
        expanded[((size_t)b * M_ + m) * C_ + c] = acc[i][j][rr] + NEGV * sfx;
      }
    }
  }
}

// ---------------------------------------------------------------------------
extern "C" void kernel_launch(void* const* d_in, const int* in_sizes, int n_in,
                              void* d_out, int out_size, void* d_ws, size_t ws_size,
                              hipStream_t stream) {
  const float* text  = (const float*)d_in[0];
  const float* mel   = (const float*)d_in[1];
  const float* noise = (const float*)d_in[2];
  const float* ratio = (const float*)d_in[3];

  const size_t BTM = (size_t)B_ * T_ * M_;   // 16777216
  float* out       = (float*)d_out;
  float* gamma_log = out;
  float* expanded  = out + BTM;

  char* w = (char*)d_ws;
  u16*   ttbuf  = (u16*)  (w + 0);           // [B][T][M] bf16   33554432 B
  u16*   Abuf   = (u16*)  (w + 33554432);    // P [B][T][M] bf16 33554432 B
  u16*   Wb     = (u16*)  (w + 67108864);    // W [B][T][M] bf16 33554432 B
  u16*   UA     = (u16*)  (w + 100663296);   // [B][T][M] bf16   33554432 B
  u16*   UB     = (u16*)  (w + 134217728);   // [B][T][M] bf16   33554432 B
  float* suffix = (float*)(w + 167772160);   // [B][T+1][C]      16809984 B
  u16*   textT  = (u16*)  (w + 184582144);   // [B][C][T] -> ends 192970752 B
  u16*   gammaT = (u16*)  (w + 0);           // overlaps ttbuf (dead after k2u)
  float* partial = (float*)(w + 67108864);   // k3 scratch in W region (pre-k2u)
  // Q/CA/CB/r00 live in the `expanded` half of d_out (k2u..k6 window, k7 overwrites)
  u16*   Bbuf = (u16*)expanded;                            // Q, 33554432 B
  float* CAa  = (float*)((char*)expanded + 33554432);      // [B][T] 32768 B
  float* CBa  = CAa + (size_t)B_ * T_;                     // [B][T] 32768 B
  float* r00  = CBa + (size_t)B_ * T_;                     // [B] 64 B

  k3a_partial<<<B_ * 8,          512, 0, stream>>>(text, partial);
  k3b_suffix <<<B_ * 8,          512, 0, stream>>>(text, partial, suffix);
  k3t_textT  <<<dim3(8, 8, 16),  256, 0, stream>>>(text, textT);
  k1_energy  <<<dim3(4, 16, 16), 256, 0, stream>>>(text, mel, noise, ratio, ttbuf);
  k2u        <<<B_ * T_,         256, 0, stream>>>(ttbuf, Wb, UA, UB, Bbuf, r00);
  k4_dp      <<<32,              128, 0, stream>>>(UA, UB, r00, Abuf, Bbuf, CAa, CBa);
  k6_combine <<<B_ * 64,         256, 0, stream>>>(Abuf, Bbuf, Wb, CAa, CBa, gamma_log, gammaT);
  k7_expanded<<<dim3(16, 4, 16), 256, 0, stream>>>(gammaT, textT, suffix, expanded);
}

// Round 12
// 412.236 us; speedup vs baseline: 1.5227x; 1.5227x over previous
//
#include <hip/hip_runtime.h>

#define B_  16
#define T_  512
#define M_  2048
#define C_  512
#define NEGV (-1e30f)
#define L2E 1.4426950408889634f
#define LN2 0.69314718055994531f
#define GRP 6
#define NG  86

typedef unsigned short u16;
typedef unsigned int   u32;
using bf16x8 = __attribute__((ext_vector_type(8))) short;
using f32x4  = __attribute__((ext_vector_type(4))) float;

__device__ __forceinline__ u16 f2bf(float x) {
  u32 u = __float_as_uint(x);
  return (u16)((u + 0x7FFFu + ((u >> 16) & 1u)) >> 16);
}
__device__ __forceinline__ float bf2f(u16 u) {
  return __uint_as_float(((u32)u) << 16);
}
__device__ __forceinline__ float rdlane63(float x) {
  return __int_as_float(__builtin_amdgcn_readlane(__float_as_int(x), 63));
}

// 64-lane inclusive add-scan via DPP (row_shr 1/2/4/8, bcast15, bcast31)
__device__ __forceinline__ float wscan_add(float x) {
  x += __int_as_float(__builtin_amdgcn_update_dpp(0, __float_as_int(x), 0x111, 0xF, 0xF, true));
  x += __int_as_float(__builtin_amdgcn_update_dpp(0, __float_as_int(x), 0x112, 0xF, 0xF, true));
  x += __int_as_float(__builtin_amdgcn_update_dpp(0, __float_as_int(x), 0x114, 0xF, 0xF, true));
  x += __int_as_float(__builtin_amdgcn_update_dpp(0, __float_as_int(x), 0x118, 0xF, 0xF, true));
  x += __int_as_float(__builtin_amdgcn_update_dpp(0, __float_as_int(x), 0x142, 0xA, 0xF, true));
  x += __int_as_float(__builtin_amdgcn_update_dpp(0, __float_as_int(x), 0x143, 0xC, 0xF, true));
  return x;
}
// lane i <- lane i-1 (wave_shr:1), lane0 <- 0
__device__ __forceinline__ float dpp_shr1(float x) {
  return __int_as_float(__builtin_amdgcn_update_dpp(0, __float_as_int(x), 0x138, 0xF, 0xF, true));
}

// ---------------------------------------------------------------------------
// K1: energy GEMM (bf16 MFMA) + gumbel + /temperature -> tt = exp(le - D) bf16
// ---------------------------------------------------------------------------
__launch_bounds__(256)
__global__ void k1_energy(const float* __restrict__ text, const float* __restrict__ mel,
                          const float* __restrict__ noise, const float* __restrict__ ratio,
                          u16* __restrict__ ttbuf)
{
  __shared__ __align__(16) short As[128][40];
  __shared__ __align__(16) short Bs[128][40];
  const int b   = blockIdx.z;
  const int t0  = blockIdx.x * 128;
  const int m0  = blockIdx.y * 128;
  const int tid = threadIdx.x;
  const int lane = tid & 63, wid = tid >> 6;
  const int wr = wid >> 1, wc = wid & 1;
  const float* Ab = text + (size_t)b * T_ * C_;
  const float* Bb = mel  + (size_t)b * M_ * C_;
  f32x4 acc[4][4];
#pragma unroll
  for (int i = 0; i < 4; ++i)
#pragma unroll
    for (int j = 0; j < 4; ++j) acc[i][j] = (f32x4){0.f, 0.f, 0.f, 0.f};

  const int kq = (tid & 7) * 4;
  const int rb = tid >> 3;
  for (int kk = 0; kk < C_; kk += 32) {
    __syncthreads();
#pragma unroll
    for (int it = 0; it < 4; ++it) {
      int r = rb + it * 32;
      float4 va = *(const float4*)(Ab + (size_t)(t0 + r) * C_ + kk + kq);
      As[r][kq + 0] = (short)f2bf(va.x); As[r][kq + 1] = (short)f2bf(va.y);
      As[r][kq + 2] = (short)f2bf(va.z); As[r][kq + 3] = (short)f2bf(va.w);
      float4 vb = *(const float4*)(Bb + (size_t)(m0 + r) * C_ + kk + kq);
      Bs[r][kq + 0] = (short)f2bf(vb.x); Bs[r][kq + 1] = (short)f2bf(vb.y);
      Bs[r][kq + 2] = (short)f2bf(vb.z); Bs[r][kq + 3] = (short)f2bf(vb.w);
    }
    __syncthreads();
    const int k0 = (lane >> 4) * 8;
    bf16x8 af[4], bfr[4];
#pragma unroll
    for (int i = 0; i < 4; ++i) {
      af[i]  = *(const bf16x8*)&As[wr * 64 + i * 16 + (lane & 15)][k0];
      bfr[i] = *(const bf16x8*)&Bs[wc * 64 + i * 16 + (lane & 15)][k0];
    }
#pragma unroll
    for (int i = 0; i < 4; ++i)
#pragma unroll
      for (int j = 0; j < 4; ++j)
        acc[i][j] = __builtin_amdgcn_mfma_f32_16x16x32_bf16(af[i], bfr[j], acc[i][j], 0, 0, 0);
  }
  const float invT = 1.0f / (0.1f + 0.9f * ratio[0]);
  const float D2 = 14.5f * invT * L2E;
#pragma unroll
  for (int i = 0; i < 4; ++i) {
#pragma unroll
    for (int j = 0; j < 4; ++j) {
#pragma unroll
      for (int rr = 0; rr < 4; ++rr) {
        int t = t0 + wr * 64 + i * 16 + (lane >> 4) * 4 + rr;
        int m = m0 + wc * 64 + j * 16 + (lane & 15);
        size_t idx = ((size_t)b * T_ + t) * M_ + m;
        float en = acc[i][j][rr] * (1.0f / 512.0f);
        float u  = noise[idx];
        float nl = -LN2 * __builtin_amdgcn_logf(u);    // -ln u  (>0)
        float g  = -LN2 * __builtin_amdgcn_logf(nl);   // -ln(-ln u)
        float le = (en + g) * invT;
        float tv = __builtin_amdgcn_exp2f(__builtin_fmaf(le, L2E, -D2));
        ttbuf[idx] = f2bf(tv);
      }
    }
  }
}

// ---------------------------------------------------------------------------
// K2u: per row t: suffix-sums of tt[t], tt[t+1] -> R_t, R_{t+1} in regs;
//      W[t]=tt_t*R_t; UB[t]=tt_t*R_{t+1}; UA[t+1][k]=tt_t[k-1]*R_{t+1}[k];
//      row T-1: Q init = S_{T-1} (x e at col M-1) -> Bbuf; t=0: r00[b]=R_0[0].
// ---------------------------------------------------------------------------
__launch_bounds__(256)
__global__ void k2u(const u16* __restrict__ tt, u16* __restrict__ W,
                    u16* __restrict__ UA, u16* __restrict__ UB,
                    u16* __restrict__ Qb, float* __restrict__ r00)
{
  __shared__ float part0[4], part1[4];
  const size_t row = blockIdx.x;               // b*T + t
  const int t = (int)(row & (T_ - 1));
  const int b = (int)(row >> 9);
  const size_t rowN = (t < T_ - 1) ? row + 1 : row;
  const int tid = threadIdx.x, lane = tid & 63, wid = tid >> 6;
  const int c0 = tid * 8;
  const u16* ttr = tt + row * M_ + c0;
  const u16* ttn = tt + rowN * M_ + c0;
  float x[8], y[8];
  { uint4 wa = *(const uint4*)ttr;
    x[0]=__uint_as_float(wa.x<<16); x[1]=__uint_as_float(wa.x&0xFFFF0000u);
    x[2]=__uint_as_float(wa.y<<16); x[3]=__uint_as_float(wa.y&0xFFFF0000u);
    x[4]=__uint_as_float(wa.z<<16); x[5]=__uint_as_float(wa.z&0xFFFF0000u);
    x[6]=__uint_as_float(wa.w<<16); x[7]=__uint_as_float(wa.w&0xFFFF0000u); }
  { uint4 wb = *(const uint4*)ttn;
    y[0]=__uint_as_float(wb.x<<16); y[1]=__uint_as_float(wb.x&0xFFFF0000u);
    y[2]=__uint_as_float(wb.y<<16); y[3]=__uint_as_float(wb.y&0xFFFF0000u);
    y[4]=__uint_as_float(wb.z<<16); y[5]=__uint_as_float(wb.z&0xFFFF0000u);
    y[6]=__uint_as_float(wb.w<<16); y[7]=__uint_as_float(wb.w&0xFFFF0000u); }
  float xm1 = (c0 == 0) ? 0.f : bf2f(ttr[-1]);

  float sx[8], sy[8];
  sx[7] = x[7]; sy[7] = y[7];
#pragma unroll
  for (int i = 6; i >= 0; --i) { sx[i] = x[i] + sx[i+1]; sy[i] = y[i] + sy[i+1]; }
  float vx = sx[0], vy = sy[0];
#pragma unroll
  for (int d = 1; d < 64; d <<= 1) {
    float tx = __shfl_down(vx, d), ty = __shfl_down(vy, d);
    if (lane < 64 - d) { vx += tx; vy += ty; }
  }
  float ex = __shfl_down(vx, 1), ey = __shfl_down(vy, 1);
  if (lane == 63) { ex = 0.f; ey = 0.f; }
  if (lane == 0) { part0[wid] = vx; part1[wid] = vy; }
  __syncthreads();
  float wex = 0.f, wey = 0.f;
  for (int w2 = wid + 1; w2 < 4; ++w2) { wex += part0[w2]; wey += part1[w2]; }
  float offx = ex + wex, offy = ey + wey;

  float rx[8], ry[8];
#pragma unroll
  for (int i = 0; i < 8; ++i) {
    rx[i] = __builtin_amdgcn_rcpf(sx[i] + offx);
    ry[i] = __builtin_amdgcn_rcpf(sy[i] + offy);
  }
  // W[t]
  { u32 o[4];
#pragma unroll
    for (int i = 0; i < 4; ++i)
      o[i] = __builtin_amdgcn_perm(__float_as_uint(x[2*i+1]*rx[2*i+1]),
                                   __float_as_uint(x[2*i]*rx[2*i]), 0x07060302u);
    *(uint4*)(W + row * M_ + c0) = make_uint4(o[0],o[1],o[2],o[3]); }

  if (t == 0 && tid == 0) r00[b] = rx[0];

  if (t == T_ - 1) {
    float q[8];
#pragma unroll
    for (int i = 0; i < 8; ++i) q[i] = sx[i] + offx;
    if (tid == 255) q[7] *= 2.718281828f;      // faithful beta_T[M-1]=1 -> e
    u32 o[4];
#pragma unroll
    for (int i = 0; i < 4; ++i)
      o[i] = __builtin_amdgcn_perm(__float_as_uint(q[2*i+1]), __float_as_uint(q[2*i]), 0x07060302u);
    *(uint4*)(Qb + ((size_t)b * T_ + T_ - 1) * M_ + c0) = make_uint4(o[0],o[1],o[2],o[3]);
  } else {
    u32 o[4];
#pragma unroll
    for (int i = 0; i < 4; ++i)
      o[i] = __builtin_amdgcn_perm(__float_as_uint(x[2*i+1]*ry[2*i+1]),
                                   __float_as_uint(x[2*i]*ry[2*i]), 0x07060302u);
    *(uint4*)(UB + row * M_ + c0) = make_uint4(o[0],o[1],o[2],o[3]);
    float ua[8];
    ua[0] = xm1 * ry[0];
#pragma unroll
    for (int i = 1; i < 8; ++i) ua[i] = x[i-1] * ry[i];
#pragma unroll
    for (int i = 0; i < 4; ++i)
      o[i] = __builtin_amdgcn_perm(__float_as_uint(ua[2*i+1]), __float_as_uint(ua[2*i]), 0x07060302u);
    *(uint4*)(UA + (row + 1) * M_ + c0) = make_uint4(o[0],o[1],o[2],o[3]);
  }
}

// ---------------------------------------------------------------------------
// K3a/K3b: suffix sums of text over t; K3t: textT transpose (unchanged)
// ---------------------------------------------------------------------------
__launch_bounds__(512)
__global__ void k3a_partial(const float* __restrict__ text, float* __restrict__ partial)
{
  const int b = blockIdx.x >> 3, ch = blockIdx.x & 7, c = threadIdx.x;
  const float* tb = text + (size_t)b * T_ * C_ + (size_t)ch * 64 * C_ + c;
  float s = 0.f;
#pragma unroll 8
  for (int tt = 0; tt < 64; ++tt) s += tb[(size_t)tt * C_];
  partial[((size_t)b * 8 + ch) * C_ + c] = s;
}

__launch_bounds__(512)
__global__ void k3b_suffix(const float* __restrict__ text, const float* __restrict__ partial,
                           float* __restrict__ suffix)
{
  const int b = blockIdx.x >> 3, ch = blockIdx.x & 7, c = threadIdx.x;
  float off = 0.f;
  for (int ch2 = ch + 1; ch2 < 8; ++ch2) off += partial[((size_t)b * 8 + ch2) * C_ + c];
  const float* tb = text + (size_t)b * T_ * C_ + (size_t)ch * 64 * C_ + c;
  float* sb = suffix + (size_t)b * (T_ + 1) * C_ + (size_t)ch * 64 * C_ + c;
  if (ch == 7) sb[(size_t)64 * C_] = 0.f;   // row T_
  float s = off;
  for (int tt = 63; tt >= 0; --tt) {
    s += tb[(size_t)tt * C_];
    sb[(size_t)tt * C_] = s;
  }
}

__launch_bounds__(256)
__global__ void k3t_textT(const float* __restrict__ text, u16* __restrict__ textT)
{
  __shared__ u16 tile[64][66];
  const int b  = blockIdx.z;
  const int t0 = blockIdx.x * 64;
  const int c0 = blockIdx.y * 64;
  const int tid = threadIdx.x;
  const int j = tid & 63, i4 = tid >> 6;
#pragma unroll
  for (int it = 0; it < 16; ++it) {
    int i = it * 4 + i4;
    tile[i][j] = f2bf(text[((size_t)b * T_ + t0 + i) * C_ + c0 + j]);
  }
  __syncthreads();
#pragma unroll
  for (int it = 0; it < 16; ++it) {
    int cc = it * 4 + i4;
    textT[((size_t)b * C_ + c0 + cc) * T_ + t0 + j] = tile[j][cc];
  }
}

// ---------------------------------------------------------------------------
// K4: alpha (blocks 0..15) / beta (blocks 16..31). 128 threads/block:
//     wave 0 = round-8 DP ALU (unchanged numerics) reading U rows from LDS;
//     wave 1 = producer staging U rows via global_load_lds (cannot be sunk),
//     GRP rows/group, double-buffered, __syncthreads() drains DMA per group.
// ---------------------------------------------------------------------------
__launch_bounds__(128, 1)
__global__ void k4_dp(const u16* __restrict__ UA, const u16* __restrict__ UB,
                      const float* __restrict__ r00,
                      u16* __restrict__ Abuf, u16* __restrict__ Bbuf,
                      float* __restrict__ CAa, float* __restrict__ CBa)
{
  __shared__ __align__(16) char ldsraw[2 * GRP * 4096];
  const int blk = blockIdx.x;
  const int b   = blk & 15;
  const int tid = threadIdx.x;
  const int lane = tid & 63;
  const int wv   = tid >> 6;
  float cum[32], Pv[32];
  float Cv;

#define PISSUE(RP_, BB, SLOT) { \
    const u16* rp_ = (RP_) + lane * 32; \
    char* lb_ = ldsraw + (((BB) * GRP + (SLOT)) * 4096); \
    __builtin_amdgcn_global_load_lds((const __attribute__((address_space(1))) void*)(rp_ + 0),  (__attribute__((address_space(3))) void*)(lb_ + 0),    16, 0, 0); \
    __builtin_amdgcn_global_load_lds((const __attribute__((address_space(1))) void*)(rp_ + 8),  (__attribute__((address_space(3))) void*)(lb_ + 1024), 16, 0, 0); \
    __builtin_amdgcn_global_load_lds((const __attribute__((address_space(1))) void*)(rp_ + 16), (__attribute__((address_space(3))) void*)(lb_ + 2048), 16, 0, 0); \
    __builtin_amdgcn_global_load_lds((const __attribute__((address_space(1))) void*)(rp_ + 24), (__attribute__((address_space(3))) void*)(lb_ + 3072), 16, 0, 0); }

  if (blk < 16) {
    // ======================= alpha =======================
    const u16* Up = UA + (size_t)b * T_ * M_;

    if (wv == 1) {
      // producer: stage rows 1..511 in groups of GRP, double-buffered
      for (int s = 0; s < GRP; ++s) {
        int r = 1 + s; if (r > T_ - 1) r = T_ - 1;
        PISSUE(Up + (size_t)r * M_, 0, s)
      }
      for (int g = 0; g < NG; ++g) {
        __syncthreads();
        if (g + 1 < NG) {
          for (int s = 0; s < GRP; ++s) {
            int r = 1 + (g + 1) * GRP + s; if (r > T_ - 1) r = T_ - 1;
            PISSUE(Up + (size_t)r * M_, (g + 1) & 1, s)
          }
        }
      }
      return;
    }

    u16* AO = Abuf + (size_t)b * T_ * M_;
    float* CO = CAa + (size_t)b * T_;

#define AF2(E, W_) { \
    cum[E]     = __uint_as_float((W_) << 16)         * Pv[(E)-1]; \
    cum[(E)+1] = __uint_as_float((W_) & 0xFFFF0000u) * Pv[E]; }

#define ASTEP_L(LB_, RIDX) { \
    const int r_ = (RIDX); \
    const char* lb_ = (LB_); \
    uint4 rw0 = *(const uint4*)(lb_ + lane * 16); \
    uint4 rw1 = *(const uint4*)(lb_ + 1024 + lane * 16); \
    uint4 rw2 = *(const uint4*)(lb_ + 2048 + lane * 16); \
    uint4 rw3 = *(const uint4*)(lb_ + 3072 + lane * 16); \
    { float pm1 = dpp_shr1(Pv[31]); \
      cum[0] = __uint_as_float(rw0.x << 16) * pm1; \
      cum[1] = __uint_as_float(rw0.x & 0xFFFF0000u) * Pv[0]; } \
    AF2(2,  rw0.y) AF2(4,  rw0.z) AF2(6,  rw0.w) \
    AF2(8,  rw1.x) AF2(10, rw1.y) AF2(12, rw1.z) AF2(14, rw1.w) \
    AF2(16, rw2.x) AF2(18, rw2.y) AF2(20, rw2.z) AF2(22, rw2.w) \
    AF2(24, rw3.x) AF2(26, rw3.y) AF2(28, rw3.z) AF2(30, rw3.w) \
    _Pragma("unroll") for (int c = 0; c < 4; ++c) \
      _Pragma("unroll") for (int k = 1; k < 8; ++k) cum[8*c+k] += cum[8*c+k-1]; \
    { float lt = (cum[7] + cum[15]) + (cum[23] + cum[31]); \
      float v_ = wscan_add(lt); \
      float exw = v_ - lt; \
      float Zt = rdlane63(v_); \
      float f0 = exw, f1 = f0 + cum[7], f2 = f1 + cum[15], f3 = f2 + cum[23]; \
      float Zc = fmaxf(Zt, 1e-35f); \
      float zr = __builtin_amdgcn_rcpf(Zc); \
      Cv += LN2 * __builtin_amdgcn_logf(Zc); \
      if (lane == 0) CO[r_] = Cv; \
      float fz0 = f0*zr, fz1 = f1*zr, fz2 = f2*zr, fz3 = f3*zr; \
      _Pragma("unroll") for (int k = 0; k < 8; ++k) { \
        Pv[k]    = __builtin_fmaf(cum[k],    zr, fz0); \
        Pv[8+k]  = __builtin_fmaf(cum[8+k],  zr, fz1); \
        Pv[16+k] = __builtin_fmaf(cum[16+k], zr, fz2); \
        Pv[24+k] = __builtin_fmaf(cum[24+k], zr, fz3); } } \
    { u32 w_[16]; \
      _Pragma("unroll") for (int d = 0; d < 16; ++d) \
        w_[d] = __builtin_amdgcn_perm(__float_as_uint(Pv[2*d+1]), __float_as_uint(Pv[2*d]), 0x07060302u); \
      uint4* op = (uint4*)(AO + (size_t)r_ * M_ + lane * 32); \
      op[0] = make_uint4(w_[0],w_[1],w_[2],w_[3]); \
      op[1] = make_uint4(w_[4],w_[5],w_[6],w_[7]); \
      op[2] = make_uint4(w_[8],w_[9],w_[10],w_[11]); \
      op[3] = make_uint4(w_[12],w_[13],w_[14],w_[15]); } \
  }

    // init: P row 0 = 1.0 everywhere; CA_0 = ln(R_0[0])
    { uint4 one4 = make_uint4(0x3F803F80u, 0x3F803F80u, 0x3F803F80u, 0x3F803F80u);
      uint4* op = (uint4*)(AO + lane * 32);
      op[0] = one4; op[1] = one4; op[2] = one4; op[3] = one4; }
    Cv = LN2 * __builtin_amdgcn_logf(r00[b]);
    if (lane == 0) CO[0] = Cv;
#pragma unroll
    for (int e = 0; e < 32; ++e) Pv[e] = 1.0f;

    for (int g = 0; g < NG; ++g) {
      __syncthreads();
      const char* gb = ldsraw + ((g & 1) * GRP) * 4096;
#pragma unroll
      for (int s = 0; s < GRP; ++s) {
        int r = 1 + g * GRP + s;
        if (r < T_) { ASTEP_L(gb + s * 4096, r) }
      }
    }
  } else {
    // ======================= beta (memory order, mirrored scans) ==========
    const u16* Up = UB + (size_t)b * T_ * M_;

    if (wv == 1) {
      // producer: stage rows t = 510 down to 0 in groups of GRP
      for (int s = 0; s < GRP; ++s) {
        int t = 510 - s; if (t < 0) t = 0;
        PISSUE(Up + (size_t)t * M_, 0, s)
      }
      for (int g = 0; g < NG; ++g) {
        __syncthreads();
        if (g + 1 < NG) {
          for (int s = 0; s < GRP; ++s) {
            int t = 510 - ((g + 1) * GRP + s); if (t < 0) t = 0;
            PISSUE(Up + (size_t)t * M_, (g + 1) & 1, s)
          }
        }
      }
      return;
    }

    const int jb = M_ - 32 - lane * 32;   // lane covers cols jb..jb+31 ascending
    u16* BO = Bbuf + (size_t)b * T_ * M_;
    float* CO = CBa + (size_t)b * T_;

#define BF2(E, W_) { \
    cum[E]     = __uint_as_float((W_) << 16)         * Pv[E]; \
    cum[(E)+1] = __uint_as_float((W_) & 0xFFFF0000u) * Pv[(E)+1]; }

#define BSTEP_L(LB_, TIDX) { \
    const int t_ = (TIDX); \
    const char* lb_ = (LB_); \
    uint4 rw0 = *(const uint4*)(lb_ + (63 - lane) * 16); \
    uint4 rw1 = *(const uint4*)(lb_ + 1024 + (63 - lane) * 16); \
    uint4 rw2 = *(const uint4*)(lb_ + 2048 + (63 - lane) * 16); \
    uint4 rw3 = *(const uint4*)(lb_ + 3072 + (63 - lane) * 16); \
    BF2(0,  rw0.x) BF2(2,  rw0.y) BF2(4,  rw0.z) BF2(6,  rw0.w) \
    BF2(8,  rw1.x) BF2(10, rw1.y) BF2(12, rw1.z) BF2(14, rw1.w) \
    BF2(16, rw2.x) BF2(18, rw2.y) BF2(20, rw2.z) BF2(22, rw2.w) \
    BF2(24, rw3.x) BF2(26, rw3.y) BF2(28, rw3.z) BF2(30, rw3.w) \
    _Pragma("unroll") for (int c = 0; c < 4; ++c) \
      _Pragma("unroll") for (int k = 6; k >= 0; --k) cum[8*c+k] += cum[8*c+k+1]; \
    { float lt = (cum[0] + cum[8]) + (cum[16] + cum[24]); \
      float v_ = wscan_add(lt); \
      float exw = v_ - lt; \
      float Zb = rdlane63(v_); \
      float f0 = exw, f1 = f0 + cum[24], f2 = f1 + cum[16], f3 = f2 + cum[8]; \
      float Zc = fmaxf(Zb, 1e-35f); \
      float zr = __builtin_amdgcn_rcpf(Zc); \
      Cv += LN2 * __builtin_amdgcn_logf(Zc); \
      if (lane == 0) CO[t_] = Cv; \
      float fz0 = f0*zr, fz1 = f1*zr, fz2 = f2*zr, fz3 = f3*zr; \
      _Pragma("unroll") for (int k = 0; k < 8; ++k) { \
        Pv[24+k] = __builtin_fmaf(cum[24+k], zr, fz0); \
        Pv[16+k] = __builtin_fmaf(cum[16+k], zr, fz1); \
        Pv[8+k]  = __builtin_fmaf(cum[8+k],  zr, fz2); \
        Pv[k]    = __builtin_fmaf(cum[k],    zr, fz3); } } \
    { u32 w_[16]; \
      _Pragma("unroll") for (int d = 0; d < 16; ++d) \
        w_[d] = __builtin_amdgcn_perm(__float_as_uint(Pv[2*d+1]), __float_as_uint(Pv[2*d]), 0x07060302u); \
      uint4* op = (uint4*)(BO + (size_t)t_ * M_ + jb); \
      op[0] = make_uint4(w_[0],w_[1],w_[2],w_[3]); \
      op[1] = make_uint4(w_[4],w_[5],w_[6],w_[7]); \
      op[2] = make_uint4(w_[8],w_[9],w_[10],w_[11]); \
      op[3] = make_uint4(w_[12],w_[13],w_[14],w_[15]); } \
  }

    // init: Q row T-1 (written by k2u) -> state; CB_{T-1} = 0
    { const uint4* ip = (const uint4*)(BO + (size_t)(T_ - 1) * M_ + jb);
      uint4 q0 = ip[0], q1 = ip[1], q2 = ip[2], q3 = ip[3];
      Pv[0]=__uint_as_float(q0.x<<16);  Pv[1]=__uint_as_float(q0.x&0xFFFF0000u);
      Pv[2]=__uint_as_float(q0.y<<16);  Pv[3]=__uint_as_float(q0.y&0xFFFF0000u);
      Pv[4]=__uint_as_float(q0.z<<16);  Pv[5]=__uint_as_float(q0.z&0xFFFF0000u);
      Pv[6]=__uint_as_float(q0.w<<16);  Pv[7]=__uint_as_float(q0.w&0xFFFF0000u);
      Pv[8]=__uint_as_float(q1.x<<16);  Pv[9]=__uint_as_float(q1.x&0xFFFF0000u);
      Pv[10]=__uint_as_float(q1.y<<16); Pv[11]=__uint_as_float(q1.y&0xFFFF0000u);
      Pv[12]=__uint_as_float(q1.z<<16); Pv[13]=__uint_as_float(q1.z&0xFFFF0000u);
      Pv[14]=__uint_as_float(q1.w<<16); Pv[15]=__uint_as_float(q1.w&0xFFFF0000u);
      Pv[16]=__uint_as_float(q2.x<<16); Pv[17]=__uint_as_float(q2.x&0xFFFF0000u);
      Pv[18]=__uint_as_float(q2.y<<16); Pv[19]=__uint_as_float(q2.y&0xFFFF0000u);
      Pv[20]=__uint_as_float(q2.z<<16); Pv[21]=__uint_as_float(q2.z&0xFFFF0000u);
      Pv[22]=__uint_as_float(q2.w<<16); Pv[23]=__uint_as_float(q2.w&0xFFFF0000u);
      Pv[24]=__uint_as_float(q3.x<<16); Pv[25]=__uint_as_float(q3.x&0xFFFF0000u);
      Pv[26]=__uint_as_float(q3.y<<16); Pv[27]=__uint_as_float(q3.y&0xFFFF0000u);
      Pv[28]=__uint_as_float(q3.z<<16); Pv[29]=__uint_as_float(q3.z&0xFFFF0000u);
      Pv[30]=__uint_as_float(q3.w<<16); Pv[31]=__uint_as_float(q3.w&0xFFFF0000u); }
    Cv = 0.f;
    if (lane == 0) CO[T_ - 1] = 0.f;

    for (int g = 0; g < NG; ++g) {
      __syncthreads();
      const char* gb = ldsraw + ((g & 1) * GRP) * 4096;
#pragma unroll
      for (int s = 0; s < GRP; ++s) {
        int t = 510 - (g * GRP + s);
        if (t >= 0) { BSTEP_L(gb + s * 4096, t) }
      }
    }
  }
}

// ---------------------------------------------------------------------------
// K6: gamma = (t<=m) ? LN2*log2(P*Q*W) + CA[t]+CB[t] : NEGV  (clamped);
//     LSE over t; gamma_log -> d_out; gammaT bf16 (masked) via LDS stash.
// ---------------------------------------------------------------------------
__launch_bounds__(256)
__global__ void k6_combine(const u16* __restrict__ Pb, const u16* __restrict__ Qb,
                           const u16* __restrict__ Wb,
                           const float* __restrict__ CAa, const float* __restrict__ CBa,
                           float* __restrict__ gamma_log, u16* __restrict__ gammaT)
{
  __shared__ u16 gst[32][514];
  __shared__ float cd[T_];
  __shared__ float smx[8][32], ssm[8][32];
  const int b  = blockIdx.x >> 6;
  const int m0 = (blockIdx.x & 63) * 32;
  const int tid = threadIdx.x;
  const int mi = tid & 31, ti = tid >> 5;
  const int m = m0 + mi;
  const size_t base = (size_t)b * T_ * M_ + m;

  cd[tid]       = CAa[b * T_ + tid]       + CBa[b * T_ + tid];
  cd[tid + 256] = CAa[b * T_ + tid + 256] + CBa[b * T_ + tid + 256];
  __syncthreads();

  float mx = -3.0e38f, s = 0.f;
  for (int t = ti; t < T_; t += 8) {
    float p  = bf2f(Pb[base + (size_t)t * M_]);
    float q  = bf2f(Qb[base + (size_t)t * M_]);
    float wv = bf2f(Wb[base + (size_t)t * M_]);
    float g;
    if (t <= m) {
      g = __builtin_fmaf(__builtin_amdgcn_logf(p * q * wv), LN2, cd[t]);
      g = fmaxf(g, -1e8f);            // underflow clamp (error << thresholds)
    } else g = NEGV;
    gst[mi][t] = f2bf(g);
    if (g > mx) { s = s * __builtin_amdgcn_exp2f((mx - g) * L2E) + 1.f; mx = g; }
    else        { s += __builtin_amdgcn_exp2f((g - mx) * L2E); }
  }
  smx[ti][mi] = mx; ssm[ti][mi] = s;
  __syncthreads();
  float Mv = smx[0][mi], Sv = ssm[0][mi];
#pragma unroll
  for (int k = 1; k < 8; ++k) {
    float Mk = smx[k][mi], Sk = ssm[k][mi];
    if (Mk > Mv) { Sv = Sv * __builtin_amdgcn_exp2f((Mv - Mk) * L2E) + Sk; Mv = Mk; }
    else         { Sv += Sk * __builtin_amdgcn_exp2f((Mk - Mv) * L2E); }
  }
  const float lse = Mv + LN2 * __builtin_amdgcn_logf(Sv);

  // pass2a: gamma_log (masked entries exact NEGV, not bf16-rounded)
  for (int t = ti; t < T_; t += 8) {
    float g = (t <= m) ? bf2f(gst[mi][t]) : NEGV;
    gamma_log[base + (size_t)t * M_] = g - lse;
  }
  // pass2b: gammaT[b, m0+k, t] from LDS stash (coalesced u32 rows)
  for (int k = 0; k < 32; ++k) {
    u32 val = *(const u32*)&gst[k][2 * tid];
    int mr = m0 + k;
    u32 lo = (2 * tid     <= mr) ? (val & 0x0000FFFFu) : 0u;
    u32 hi = (2 * tid + 1 <= mr) ? (val & 0xFFFF0000u) : 0u;
    ((u32*)gammaT)[((((size_t)b * M_ + m0 + k) * T_) >> 1) + tid] = lo | hi;
  }
}

// ---------------------------------------------------------------------------
// K7: expanded[b,m,c] = sum_t gammaT[m,t]*textT[c,t]  + (-1e30)*suffix[m+1,c]
// ---------------------------------------------------------------------------
__launch_bounds__(256)
__global__ void k7_expanded(const u16* __restrict__ gammaT, const u16* __restrict__ textT,
                            const float* __restrict__ suffix, float* __restrict__ expanded)
{
  __shared__ __align__(16) short As[128][40];
  __shared__ __align__(16) short Bs[128][40];
  const int b   = blockIdx.z;
  const int m0  = blockIdx.x * 128;
  const int c0  = blockIdx.y * 128;
  const int tid = threadIdx.x;
  const int lane = tid & 63, wid = tid >> 6;
  const int wr = wid >> 1, wc = wid & 1;
  const u16* Ab = gammaT + (size_t)b * M_ * T_;
  const u16* Bb = textT  + (size_t)b * C_ * T_;
  f32x4 acc[4][4];
#pragma unroll
  for (int i = 0; i < 4; ++i)
#pragma unroll
    for (int j = 0; j < 4; ++j) acc[i][j] = (f32x4){0.f, 0.f, 0.f, 0.f};

  const int ko  = (tid & 3) * 8;
  const int rb2 = tid >> 2;
  for (int kk = 0; kk < T_; kk += 32) {
    __syncthreads();
#pragma unroll
    for (int it = 0; it < 2; ++it) {
      int r = rb2 + it * 64;
      *(uint4*)&As[r][ko] = *(const uint4*)(Ab + (size_t)(m0 + r) * T_ + kk + ko);
      *(uint4*)&Bs[r][ko] = *(const uint4*)(Bb + (size_t)(c0 + r) * T_ + kk + ko);
    }
    __syncthreads();
    const int k0 = (lane >> 4) * 8;
    bf16x8 af[4], bfr[4];
#pragma unroll
    for (int i = 0; i < 4; ++i) {
      af[i]  = *(const bf16x8*)&As[wr * 64 + i * 16 + (lane & 15)][k0];
      bfr[i] = *(const bf16x8*)&Bs[wc * 64 + i * 16 + (lane & 15)][k0];
    }
#pragma unroll
    for (int i = 0; i < 4; ++i)
#pragma unroll
      for (int j = 0; j < 4; ++j)
        acc[i][j] = __builtin_amdgcn_mfma_f32_16x16x32_bf16(af[i], bfr[j], acc[i][j], 0, 0, 0);
  }
#pragma unroll
  for (int i = 0; i < 4; ++i) {
#pragma unroll
    for (int j = 0; j < 4; ++j) {
#pragma unroll
      for (int rr = 0; rr < 4; ++rr) {
        int m = m0 + wr * 64 + i * 16 + (lane >> 4) * 4 + rr;
        int c = c0 + wc * 64 + j * 16 + (lane & 15);
        int sidx = (m + 1 < T_) ? (m + 1) : T_;
        float sfx = suffix[((size_t)b * (T_ + 1) + sidx) * C_ + c];
        expanded[((size_t)b * M_ + m) * C_ + c] = acc[i][j][rr] + NEGV * sfx;
      }
    }
  }
}

// ---------------------------------------------------------------------------
extern "C" void kernel_launch(void* const* d_in, const int* in_sizes, int n_in,
                              void* d_out, int out_size, void* d_ws, size_t ws_size,
                              hipStream_t stream) {
  const float* text  = (const float*)d_in[0];
  const float* mel   = (const float*)d_in[1];
  const float* noise = (const float*)d_in[2];
  const float* ratio = (const float*)d_in[3];

  const size_t BTM = (size_t)B_ * T_ * M_;   // 16777216
  float* out       = (float*)d_out;
  float* gamma_log = out;
  float* expanded  = out + BTM;

  char* w = (char*)d_ws;
  u16*   ttbuf  = (u16*)  (w + 0);           // [B][T][M] bf16   33554432 B
  u16*   Abuf   = (u16*)  (w + 33554432);    // P [B][T][M] bf16 33554432 B
  u16*   Wb     = (u16*)  (w + 67108864);    // W [B][T][M] bf16 33554432 B
  u16*   UA     = (u16*)  (w + 100663296);   // [B][T][M] bf16   33554432 B
  u16*   UB     = (u16*)  (w + 134217728);   // [B][T][M] bf16   33554432 B
  float* suffix = (float*)(w + 167772160);   // [B][T+1][C]      16809984 B
  u16*   textT  = (u16*)  (w + 184582144);   // [B][C][T] -> ends 192970752 B
  u16*   gammaT = (u16*)  (w + 0);           // overlaps ttbuf (dead after k2u)
  float* partial = (float*)(w + 67108864);   // k3 scratch in W region (pre-k2u)
  // Q/CA/CB/r00 live in the `expanded` half of d_out (k2u..k6 window, k7 overwrites)
  u16*   Bbuf = (u16*)expanded;                            // Q, 33554432 B
  float* CAa  = (float*)((char*)expanded + 33554432);      // [B][T] 32768 B
  float* CBa  = CAa + (size_t)B_ * T_;                     // [B][T] 32768 B
  float* r00  = CBa + (size_t)B_ * T_;                     // [B] 64 B

  k3a_partial<<<B_ * 8,          512, 0, stream>>>(text, partial);
  k3b_suffix <<<B_ * 8,          512, 0, stream>>>(text, partial, suffix);
  k3t_textT  <<<dim3(8, 8, 16),  256, 0, stream>>>(text, textT);
  k1_energy  <<<dim3(4, 16, 16), 256, 0, stream>>>(text, mel, noise, ratio, ttbuf);
  k2u        <<<B_ * T_,         256, 0, stream>>>(ttbuf, Wb, UA, UB, Bbuf, r00);
  k4_dp      <<<32,              128, 0, stream>>>(UA, UB, r00, Abuf, Bbuf, CAa, CBa);
  k6_combine <<<B_ * 64,         256, 0, stream>>>(Abuf, Bbuf, Wb, CAa, CBa, gamma_log, gammaT);
  k7_expanded<<<dim3(16, 4, 16), 256, 0, stream>>>(gammaT, textT, suffix, expanded);
}